// Round 1
// baseline (684.660 us; speedup 1.0000x reference)
//
#include <hip/hip_runtime.h>

// Problem constants (fixed): N=1, C=128, H=W=512, p=2
#define HW (512 * 512)     // 262144 pixels per plane
#define CH 64              // channels per conv
#define NBLK 2048          // homogeneous blocks
#define PIXB 128           // conv pixels per block (2 per lane, float2)
#define COPY_R 16          // float4 copy iterations per thread

// Homogeneous-block fused kernel:
//   every block: (a) conv for its 128 pixels — 4 waves, each wave owns 16 output
//   channels (wave-uniform weight rows -> s_load), each lane owns a float2 pixel
//   pair -> acc = 16 x float2 = 32 VGPRs, NO spills; (b) a 1/2048 slice of the
//   odd-plane float4 passthrough copy. No role split -> no load-imbalance tail.
__global__ __launch_bounds__(256, 4) void fused_exchange_kernel(
    const float* __restrict__ lst, const float* __restrict__ gui,
    const float* __restrict__ w1, const float* __restrict__ b1,
    const float* __restrict__ w2, const float* __restrict__ b2,
    float* __restrict__ out_lst, float* __restrict__ out_gui)
{
    const int b    = blockIdx.x;
    const int tid  = threadIdx.x;
    const int lane = tid & 63;
    // wave-uniform k-group (0..3): forces SGPR -> weight rows stay s_load
    const int kg   = __builtin_amdgcn_readfirstlane(tid >> 6);
    const int pix  = b * PIXB + lane * 2;

    // ---------------- conv passes (exact fp32) ----------------
    auto conv_pass = [&](const float* __restrict__ src, const float* __restrict__ w,
                         const float* __restrict__ bias, float* __restrict__ dst) {
        const float* wbase = w + (size_t)(kg * 16) * CH;

        float2 acc[16];
        #pragma unroll
        for (int k = 0; k < 16; ++k) {
            const float bb = bias[kg * 16 + k];
            acc[k].x = bb; acc[k].y = bb;
        }

        float2 x[8];
        #pragma unroll
        for (int j = 0; j < 8; ++j)
            x[j] = *(const float2*)(src + (size_t)(2 * j) * HW + pix);

        auto fma_chunk = [&](int c0, const float2* xv) {
            #pragma unroll
            for (int k = 0; k < 16; ++k) {
                const float* wr = wbase + k * CH + c0;   // wave-uniform -> s_load
                float ax = acc[k].x, ay = acc[k].y;
                #pragma unroll
                for (int j = 0; j < 8; ++j) {
                    ax = fmaf(wr[j], xv[j].x, ax);
                    ay = fmaf(wr[j], xv[j].y, ay);
                }
                acc[k].x = ax; acc[k].y = ay;
            }
        };

        // double-buffered c-chunks: next 8 plane loads in flight under 256 FMAs
        for (int c0 = 0; c0 < CH - 8; c0 += 8) {
            float2 xn[8];
            #pragma unroll
            for (int j = 0; j < 8; ++j)
                xn[j] = *(const float2*)(src + (size_t)(2 * (c0 + 8 + j)) * HW + pix);
            fma_chunk(c0, x);
            #pragma unroll
            for (int j = 0; j < 8; ++j) x[j] = xn[j];
        }
        fma_chunk(CH - 8, x);

        #pragma unroll
        for (int k = 0; k < 16; ++k)
            *(float2*)(dst + (size_t)(2 * (kg * 16 + k)) * HW + pix) = acc[k];
    };

    conv_pass(gui, w2, b2, out_lst);   // out_lst[2k] = w2 @ gui_even + b2
    conv_pass(lst, w1, b1, out_gui);   // out_gui[2k] = w1 @ lst_even + b1

    // ---------------- odd-plane passthrough copy (float4) ----------------
    {
        // blocks [0,1024) copy lst's odd planes, [1024,2048) copy gui's.
        // Each tensor's odd-float4 space: 64 planes * 65536 float4 = 2^22 elems.
        const float4* src = (b < 1024) ? (const float4*)lst : (const float4*)gui;
        float4*       dst = (b < 1024) ? (float4*)out_lst  : (float4*)out_gui;
        const int base = (b & 1023) * (256 * COPY_R) + tid;

        #pragma unroll
        for (int r = 0; r < COPY_R; ++r) {
            const int idx = base + r * 256;       // 0 .. 2^22-1, dense, coalesced
            const int c   = idx >> 16;            // odd-plane index 0..63
            const int j   = idx & 0xFFFF;         // float4 within plane
            const int off = ((2 * c + 1) << 16) + j;
            dst[off] = src[off];
        }
    }
}

extern "C" void kernel_launch(void* const* d_in, const int* in_sizes, int n_in,
                              void* d_out, int out_size, void* d_ws, size_t ws_size,
                              hipStream_t stream) {
    const float* lst = (const float*)d_in[0];
    const float* gui = (const float*)d_in[1];
    const float* w1  = (const float*)d_in[2];
    const float* b1  = (const float*)d_in[3];
    const float* w2  = (const float*)d_in[4];
    const float* b2  = (const float*)d_in[5];
    // d_in[6] is p; fixed at 2.

    float* out_lst = (float*)d_out;
    float* out_gui = out_lst + (size_t)128 * HW;

    fused_exchange_kernel<<<NBLK, 256, 0, stream>>>(
        lst, gui, w1, b1, w2, b2, out_lst, out_gui);
}

// Round 2
// 590.484 us; speedup vs baseline: 1.1595x; 1.1595x over previous
//
#include <hip/hip_runtime.h>

// Problem constants (fixed): N=1, C=128, H=W=512, p=2
#define HW (512 * 512)     // 262144 pixels per plane
#define CH 64              // channels per conv
#define NBLK 2048          // homogeneous blocks
#define PIXB 128           // conv pixels per block (2 per lane, float2)
#define COPY_R 16          // float4 copy iterations per thread

// Homogeneous-block fused kernel, v2:
//   - NO explicit double-buffer (R1's xn[] pushed regs past the launch_bounds
//     cap -> scratch spills -> +300 MB of HBM write traffic). Fully-unrolled
//     c-chunks + (256,2) register budget let the compiler pipeline loads itself.
//   - sched_barrier(0) between passes keeps each region's register pressure
//     bounded (no cross-pass load hoisting).
__global__ __launch_bounds__(256, 2) void fused_exchange_kernel(
    const float* __restrict__ lst, const float* __restrict__ gui,
    const float* __restrict__ w1, const float* __restrict__ b1,
    const float* __restrict__ w2, const float* __restrict__ b2,
    float* __restrict__ out_lst, float* __restrict__ out_gui)
{
    const int b    = blockIdx.x;
    const int tid  = threadIdx.x;
    const int lane = tid & 63;
    // wave-uniform k-group (0..3): weight rows stay on the s_load path
    const int kg   = __builtin_amdgcn_readfirstlane(tid >> 6);
    const int pix  = b * PIXB + lane * 2;

    // ---------------- conv passes (exact fp32) ----------------
    auto conv_pass = [&](const float* __restrict__ src, const float* __restrict__ w,
                         const float* __restrict__ bias, float* __restrict__ dst) {
        const float* wbase = w + (size_t)(kg * 16) * CH;
        const float* sp    = src + pix;                        // lane base, even planes
        float*       dp    = dst + (size_t)(kg * 32) * HW + pix;

        float2 acc[16];
        #pragma unroll
        for (int k = 0; k < 16; ++k) {
            const float bb = bias[kg * 16 + k];
            acc[k].x = bb; acc[k].y = bb;
        }

        #pragma unroll
        for (int c0 = 0; c0 < CH; c0 += 8) {                   // 8 chunks, all offsets static
            float2 x[8];
            #pragma unroll
            for (int j = 0; j < 8; ++j)
                x[j] = *(const float2*)(sp + (size_t)(2 * (c0 + j)) * HW);
            #pragma unroll
            for (int k = 0; k < 16; ++k) {
                const float* wr = wbase + k * CH + c0;         // wave-uniform -> s_load
                float ax = acc[k].x, ay = acc[k].y;
                #pragma unroll
                for (int j = 0; j < 8; ++j) {
                    ax = fmaf(wr[j], x[j].x, ax);
                    ay = fmaf(wr[j], x[j].y, ay);
                }
                acc[k].x = ax; acc[k].y = ay;
            }
        }

        #pragma unroll
        for (int k = 0; k < 16; ++k)
            *(float2*)(dp + (size_t)(2 * k) * HW) = acc[k];
    };

    conv_pass(gui, w2, b2, out_lst);   // out_lst[2k] = w2 @ gui_even + b2
    __builtin_amdgcn_sched_barrier(0); // keep pass regions separate (reg pressure)
    conv_pass(lst, w1, b1, out_gui);   // out_gui[2k] = w1 @ lst_even + b1
    __builtin_amdgcn_sched_barrier(0);

    // ---------------- odd-plane passthrough copy (float4) ----------------
    {
        // blocks [0,1024) copy lst's odd planes, [1024,2048) copy gui's.
        // Each tensor's odd-float4 space: 64 planes * 65536 float4 = 2^22 elems.
        const float4* src = (b < 1024) ? (const float4*)lst : (const float4*)gui;
        float4*       dst = (b < 1024) ? (float4*)out_lst  : (float4*)out_gui;
        const int base = (b & 1023) * (256 * COPY_R) + tid;

        #pragma unroll
        for (int r = 0; r < COPY_R; ++r) {
            const int idx = base + r * 256;       // 0 .. 2^22-1, dense, coalesced
            const int c   = idx >> 16;            // odd-plane index 0..63
            const int j   = idx & 0xFFFF;         // float4 within plane
            const int off = ((2 * c + 1) << 16) + j;
            dst[off] = src[off];
        }
    }
}

extern "C" void kernel_launch(void* const* d_in, const int* in_sizes, int n_in,
                              void* d_out, int out_size, void* d_ws, size_t ws_size,
                              hipStream_t stream) {
    const float* lst = (const float*)d_in[0];
    const float* gui = (const float*)d_in[1];
    const float* w1  = (const float*)d_in[2];
    const float* b1  = (const float*)d_in[3];
    const float* w2  = (const float*)d_in[4];
    const float* b2  = (const float*)d_in[5];
    // d_in[6] is p; fixed at 2.

    float* out_lst = (float*)d_out;
    float* out_gui = out_lst + (size_t)128 * HW;

    fused_exchange_kernel<<<NBLK, 256, 0, stream>>>(
        lst, gui, w1, b1, w2, b2, out_lst, out_gui);
}